// Round 3
// baseline (6088.627 us; speedup 1.0000x reference)
//
#include <hip/hip_runtime.h>
#include <hip/hip_bf16.h>

#define NBMAX 256   // max coarse buckets
#define RSH   8     // bucket = key >> 8   (256 rows per bucket)
#define RPB   256   // rows per bucket
#define TILE  4096  // edges per scatter tile
#define KPT   16    // TILE / 256 threads

// ---------------- coarse bucket histogram ----------------
__global__ void bucket_hist(const int* __restrict__ key, int* __restrict__ gcnt, int nnz) {
    __shared__ int h[NBMAX];
    h[threadIdx.x] = 0;
    __syncthreads();
    for (int i = blockIdx.x * blockDim.x + threadIdx.x; i < nnz; i += gridDim.x * blockDim.x)
        atomicAdd(&h[key[i] >> RSH], 1);
    __syncthreads();
    int v = h[threadIdx.x];
    if (v) atomicAdd(&gcnt[threadIdx.x], v);
}

// ---------------- exclusive scan (single block, nb<=256) ----------------
__global__ void scan_offs(const int* __restrict__ gcnt, int* __restrict__ offs,
                          int* __restrict__ cursor, int nb, int nnz) {
    __shared__ int tmp[NBMAX];
    int tid = threadIdx.x;
    int v = (tid < nb) ? gcnt[tid] : 0;
    tmp[tid] = v;
    __syncthreads();
    for (int off = 1; off < NBMAX; off <<= 1) {
        int t = (tid >= off) ? tmp[tid - off] : 0;
        __syncthreads();
        tmp[tid] += t;
        __syncthreads();
    }
    if (tid < nb) { int e = tmp[tid] - v; offs[tid] = e; cursor[tid] = e; }
    if (tid == 0) offs[nb] = nnz;
}

// ---------------- staged (coalesced) bucket scatter ----------------
// Tile of 4096 edges: LDS hist -> LDS scan -> rank -> reorder in LDS ->
// coalesced runs (~tile/NB edges contiguous per bucket) to global.
__global__ __launch_bounds__(256) void staged_scatter(
        const int* __restrict__ key, const int* __restrict__ other,
        const float* __restrict__ vals, int* __restrict__ cursor,
        uint2* __restrict__ edges, int nnz) {
    __shared__ int lhist[NBMAX], lofs[NBMAX], lbase[NBMAX], lcnt[NBMAX];
    __shared__ uint2 stage[TILE];
    __shared__ int   sslot[TILE];
    int tid = threadIdx.x;
    int ntiles = (nnz + TILE - 1) / TILE;
    for (int tile = blockIdx.x; tile < ntiles; tile += gridDim.x) {
        int tbeg = tile * TILE;
        int n = nnz - tbeg; if (n > TILE) n = TILE;
        lhist[tid] = 0; lcnt[tid] = 0;
        __syncthreads();
        int myb[KPT]; unsigned myo[KPT]; float myv[KPT];
        #pragma unroll
        for (int k = 0; k < KPT; ++k) {
            int s = k * 256 + tid;
            if (s < n) {
                int i = tbeg + s;
                int ky = key[i];
                myb[k] = ky >> RSH;
                myo[k] = (unsigned)other[i] | ((unsigned)(ky & (RPB - 1)) << 16);
                myv[k] = vals[i];
                atomicAdd(&lhist[myb[k]], 1);
            } else myb[k] = -1;
        }
        __syncthreads();
        int h = lhist[tid];
        lofs[tid] = h;
        __syncthreads();
        for (int off = 1; off < NBMAX; off <<= 1) {
            int t = (tid >= off) ? lofs[tid - off] : 0;
            __syncthreads();
            lofs[tid] += t;
            __syncthreads();
        }
        lofs[tid] -= h;                                  // exclusive scan
        if (h > 0) lbase[tid] = atomicAdd(&cursor[tid], h);  // reserve global range
        __syncthreads();
        #pragma unroll
        for (int k = 0; k < KPT; ++k) {
            if (myb[k] >= 0) {
                int r  = atomicAdd(&lcnt[myb[k]], 1);
                int ls = lofs[myb[k]] + r;
                stage[ls] = make_uint2(myo[k], __float_as_uint(myv[k]));
                sslot[ls] = lbase[myb[k]] + r;           // consecutive within bucket run
            }
        }
        __syncthreads();
        #pragma unroll
        for (int k = 0; k < KPT; ++k) {
            int s = k * 256 + tid;
            if (s < n) edges[sslot[s]] = stage[s];       // coalesced runs
        }
        __syncthreads();
    }
}

// ---------------- LDS-accumulating gather ----------------
// Block = (bucket b, slice s). 64KB LDS tile = 256 rows x 64 dims.
// Edge broadcast via shfl; lane d: ds_add_f32 acc[lrow*64+d] += v*x[other*64+d].
// Flush: one global atomicAdd per touched element (out pre-zeroed).
__global__ __launch_bounds__(256) void bucket_gather(
        const int* __restrict__ offs, const uint2* __restrict__ edges,
        const float* __restrict__ x, float* __restrict__ out,
        int nrows, int S) {
    __shared__ float acc[RPB * 64];
    int tid = threadIdx.x, lane = tid & 63, wave = tid >> 6;
    int b = blockIdx.x / S, s = blockIdx.x % S;
    for (int i = tid; i < RPB * 64; i += 256) acc[i] = 0.f;
    int beg = offs[b], end = offs[b + 1];
    int len = end - beg;
    int chunk = (len + S - 1) / S;
    int mb = beg + s * chunk;
    int me = mb + chunk; if (me > end) me = end;
    __syncthreads();
    for (int base = mb + wave * 64; base < me; base += 256) {
        int n = me - base; if (n > 64) n = 64;
        uint2 e = make_uint2(0u, 0u);
        if (lane < n) e = edges[base + lane];            // 512B coalesced per wave
        for (int j = 0; j < n; ++j) {
            unsigned pk = (unsigned)__shfl((int)e.x, j);
            float    v  = __uint_as_float(__shfl((int)e.y, j));
            int oth  = pk & 0xFFFF;
            int lrow = pk >> 16;
            float xv = x[((size_t)oth << 6) + lane];     // 256B coalesced
            atomicAdd(&acc[(lrow << 6) + lane], v * xv); // ds_add_f32, 2-way banks = free
        }
    }
    __syncthreads();
    int rowbase = b << RSH;
    for (int i = tid; i < RPB * 64; i += 256) {
        int gr = rowbase + (i >> 6);
        float v = acc[i];
        if (gr < nrows && v != 0.f)
            atomicAdd(&out[((size_t)gr << 6) + (i & 63)], v);
    }
}

// ---------------- fallback: round-1 atomic scatter ----------------
__global__ void spmm_scatter_kernel(const int* __restrict__ rows, const int* __restrict__ cols,
                                    const float* __restrict__ vals,
                                    const float* __restrict__ s_emb, const float* __restrict__ p_emb,
                                    float* __restrict__ out_s, float* __restrict__ out_p, int nnz) {
    long long t = (long long)blockIdx.x * blockDim.x + threadIdx.x;
    int e = (int)(t >> 6);
    int d = (int)(t & 63);
    if (e >= nnz) return;
    int r = rows[e];
    int c = cols[e];
    float v = vals[e];
    atomicAdd(&out_s[(size_t)r * 64 + d], v * p_emb[(size_t)c * 64 + d]);
    atomicAdd(&out_p[(size_t)c * 64 + d], v * s_emb[(size_t)r * 64 + d]);
}

// ---------------- host ----------------
static void run_dir(const int* key, const int* other, const float* vals,
                    const float* x, float* out, int nrows, int nnz,
                    uint2* edges, int* gcnt, int* offs, int* cursor,
                    hipStream_t stream) {
    int nb = (nrows + RPB - 1) >> RSH;
    hipMemsetAsync(gcnt, 0, NBMAX * sizeof(int), stream);
    bucket_hist<<<512, 256, 0, stream>>>(key, gcnt, nnz);
    scan_offs<<<1, NBMAX, 0, stream>>>(gcnt, offs, cursor, nb, nnz);
    int ntiles = (nnz + TILE - 1) / TILE;
    staged_scatter<<<ntiles, 256, 0, stream>>>(key, other, vals, cursor, edges, nnz);
    int S = (768 + nb - 1) / nb; if (S < 1) S = 1;
    bucket_gather<<<nb * S, 256, 0, stream>>>(offs, edges, x, out, nrows, S);
}

extern "C" void kernel_launch(void* const* d_in, const int* in_sizes, int n_in,
                              void* d_out, int out_size, void* d_ws, size_t ws_size,
                              hipStream_t stream) {
    const float* s_emb   = (const float*)d_in[0];
    const float* p_emb   = (const float*)d_in[1];
    const int*   a_rows  = (const int*)d_in[2];
    const int*   a_cols  = (const int*)d_in[3];
    const float* a_vals  = (const float*)d_in[4];
    const int*   ia_rows = (const int*)d_in[5];
    const int*   ia_cols = (const int*)d_in[6];
    const float* ia_vals = (const float*)d_in[7];

    const int NS  = in_sizes[0] / 64;
    const int NP  = in_sizes[1] / 64;
    const int nnz = in_sizes[2];

    float* out = (float*)d_out;
    float* out_sc  = out;
    float* out_sic = out_sc  + (size_t)NS * 64;
    float* out_pc  = out_sic + (size_t)NS * 64;
    float* out_pic = out_pc  + (size_t)NP * 64;

    hipMemsetAsync(d_out, 0, (size_t)out_size * sizeof(float), stream);

    const size_t need = (size_t)nnz * sizeof(uint2) + 3 * (NBMAX + 1) * sizeof(int) + 64;
    const bool packable = (NS <= 0xFFFF + 1) && (NP <= 0xFFFF + 1) &&
                          (NS <= NBMAX * RPB) && (NP <= NBMAX * RPB) &&
                          (NS < 0x10000) && (NP < 0x10000);

    if (ws_size < need || !packable) {
        const long long total = (long long)nnz * 64;
        const int grid = (int)((total + 255) / 256);
        spmm_scatter_kernel<<<grid, 256, 0, stream>>>(a_rows, a_cols, a_vals, s_emb, p_emb,
                                                      out_sc, out_pc, nnz);
        spmm_scatter_kernel<<<grid, 256, 0, stream>>>(ia_rows, ia_cols, ia_vals, s_emb, p_emb,
                                                      out_sic, out_pic, nnz);
        return;
    }

    char* w = (char*)d_ws;
    uint2* edges  = (uint2*)w;  w += (size_t)nnz * sizeof(uint2);
    int*   gcnt   = (int*)w;    w += (NBMAX + 1) * sizeof(int);
    int*   offs   = (int*)w;    w += (NBMAX + 1) * sizeof(int);
    int*   cursor = (int*)w;

    // (student_c, student_ic, problem_c, problem_ic) — note output order!
    run_dir(a_rows,  a_cols,  a_vals,  p_emb, out_sc,  NS, nnz, edges, gcnt, offs, cursor, stream);
    run_dir(a_cols,  a_rows,  a_vals,  s_emb, out_pc,  NP, nnz, edges, gcnt, offs, cursor, stream);
    run_dir(ia_rows, ia_cols, ia_vals, p_emb, out_sic, NS, nnz, edges, gcnt, offs, cursor, stream);
    run_dir(ia_cols, ia_rows, ia_vals, s_emb, out_pic, NP, nnz, edges, gcnt, offs, cursor, stream);
}

// Round 4
// 861.402 us; speedup vs baseline: 7.0683x; 7.0683x over previous
//
#include <hip/hip_runtime.h>
#include <hip/hip_bf16.h>

#define NBMAX 256   // max coarse buckets
#define TILE  4096  // edges per staged-scatter tile
#define KPT   16    // TILE / 256

// ---------------- phase A1: coarse bucket histogram ----------------
__global__ void bucket_hist(const int* __restrict__ key, int* __restrict__ gcnt,
                            int nnz, int rsh) {
    __shared__ int h[NBMAX];
    h[threadIdx.x] = 0;
    __syncthreads();
    for (int i = blockIdx.x * blockDim.x + threadIdx.x; i < nnz; i += gridDim.x * blockDim.x)
        atomicAdd(&h[key[i] >> rsh], 1);
    __syncthreads();
    int v = h[threadIdx.x];
    if (v) atomicAdd(&gcnt[threadIdx.x], v);
}

// ---------------- phase A2: bucket offsets (1 block) ----------------
__global__ void scan_offs(const int* __restrict__ gcnt, int* __restrict__ boffs,
                          int* __restrict__ bcursor, int nb, int nnz) {
    __shared__ int tmp[NBMAX];
    int tid = threadIdx.x;
    int v = (tid < nb) ? gcnt[tid] : 0;
    tmp[tid] = v;
    __syncthreads();
    for (int off = 1; off < NBMAX; off <<= 1) {
        int t = (tid >= off) ? tmp[tid - off] : 0;
        __syncthreads();
        tmp[tid] += t;
        __syncthreads();
    }
    if (tid < nb) { int e = tmp[tid] - v; boffs[tid] = e; bcursor[tid] = e; }
    if (tid == 0) boffs[nb] = nnz;
}

// ---------------- phase A3: staged coalesced bucket scatter ----------------
// Tile of 4096 edges: LDS hist -> scan -> rank -> LDS reorder -> coalesced
// bucket runs to global. pack e.x = other | (lrow << 16) (other < 65536).
__global__ __launch_bounds__(256) void staged_scatter(
        const int* __restrict__ key, const int* __restrict__ other,
        const float* __restrict__ vals, int* __restrict__ cursor,
        uint2* __restrict__ edges, int nnz, int rsh) {
    __shared__ int lhist[NBMAX], lofs[NBMAX], lbase[NBMAX], lcnt[NBMAX];
    __shared__ uint2 stage[TILE];
    __shared__ int   sslot[TILE];
    int tid = threadIdx.x;
    int lmask = (1 << rsh) - 1;
    int ntiles = (nnz + TILE - 1) / TILE;
    for (int tile = blockIdx.x; tile < ntiles; tile += gridDim.x) {
        int tbeg = tile * TILE;
        int n = nnz - tbeg; if (n > TILE) n = TILE;
        lhist[tid] = 0; lcnt[tid] = 0;
        __syncthreads();
        int myb[KPT]; unsigned myo[KPT]; float myv[KPT];
        #pragma unroll
        for (int k = 0; k < KPT; ++k) {
            int s = k * 256 + tid;
            if (s < n) {
                int i = tbeg + s;
                int ky = key[i];
                myb[k] = ky >> rsh;
                myo[k] = (unsigned)other[i] | ((unsigned)(ky & lmask) << 16);
                myv[k] = vals[i];
                atomicAdd(&lhist[myb[k]], 1);
            } else myb[k] = -1;
        }
        __syncthreads();
        int h = lhist[tid];
        lofs[tid] = h;
        __syncthreads();
        for (int off = 1; off < NBMAX; off <<= 1) {
            int t = (tid >= off) ? lofs[tid - off] : 0;
            __syncthreads();
            lofs[tid] += t;
            __syncthreads();
        }
        lofs[tid] -= h;
        if (h > 0) lbase[tid] = atomicAdd(&cursor[tid], h);
        __syncthreads();
        #pragma unroll
        for (int k = 0; k < KPT; ++k) {
            if (myb[k] >= 0) {
                int r  = atomicAdd(&lcnt[myb[k]], 1);
                int ls = lofs[myb[k]] + r;
                stage[ls] = make_uint2(myo[k], __float_as_uint(myv[k]));
                sslot[ls] = lbase[myb[k]] + r;
            }
        }
        __syncthreads();
        #pragma unroll
        for (int k = 0; k < KPT; ++k) {
            int s = k * 256 + tid;
            if (s < n) edges[sslot[s]] = stage[s];
        }
        __syncthreads();
    }
}

// ---------------- phase B: within-bucket full row sort ----------------
// One block per bucket. Local hist+scan gives per-row offsets (published to
// offs[]), then permute: random 8B stores confined to this bucket's
// ~130-650KB span -> full-line assembly in one XCD's L2.
__global__ __launch_bounds__(1024) void row_scatter(
        const uint2* __restrict__ edges1, const int* __restrict__ boffs,
        uint2* __restrict__ edges2, int* __restrict__ offs,
        int nrows, int rsh, int nb) {
    __shared__ int lhist[NBMAX], lcur[NBMAX], tmp[NBMAX];
    int tid = threadIdx.x;
    int b = blockIdx.x;
    int rpb = 1 << rsh;
    int beg = boffs[b], end = boffs[b + 1];
    if (tid < NBMAX) lhist[tid] = 0;
    __syncthreads();
    for (int i = beg + tid; i < end; i += 1024)
        atomicAdd(&lhist[edges1[i].x >> 16], 1);   // upper 16 bits == lrow
    __syncthreads();
    int h = (tid < NBMAX) ? lhist[tid] : 0;
    if (tid < NBMAX) tmp[tid] = h;
    __syncthreads();
    for (int off = 1; off < NBMAX; off <<= 1) {
        int t = (tid < NBMAX && tid >= off) ? tmp[tid - off] : 0;
        __syncthreads();
        if (tid < NBMAX) tmp[tid] += t;
        __syncthreads();
    }
    if (tid < NBMAX) {
        int base = beg + tmp[tid] - h;             // exclusive scan
        lcur[tid] = base;
        int row = (b << rsh) + tid;
        if (tid < rpb && row < nrows) offs[row] = base;
    }
    if (b == 0 && tid == 0) offs[nrows] = boffs[nb];
    __syncthreads();
    for (int i = beg + tid; i < end; i += 1024) {
        uint2 e = edges1[i];
        int slot = atomicAdd(&lcur[e.x >> 16], 1);
        edges2[slot] = make_uint2(e.x & 0xFFFFu, e.y);
    }
}

// ---------------- phase C: per-row wave gather, 8-deep pipelined ----------------
// One 64-lane wave per output row; lane = dim. Edges loaded 64 at a time
// (coalesced), broadcast via shfl; 8 independent 256B x-gathers in flight.
// Every output element written exactly once -> no atomics, no output memset.
__global__ __launch_bounds__(256) void row_gather(
        const int* __restrict__ offs, const uint2* __restrict__ edges,
        const float* __restrict__ x, float* __restrict__ out, int nrows) {
    int r = blockIdx.x * 4 + (threadIdx.x >> 6);
    int lane = threadIdx.x & 63;
    if (r >= nrows) return;
    int beg = offs[r], end = offs[r + 1];
    float acc = 0.f;
    for (int base = beg; base < end; base += 64) {
        int n = end - base; if (n > 64) n = 64;
        uint2 e = make_uint2(0u, 0u);              // inactive lanes: row 0, val 0
        if (lane < n) e = edges[base + lane];
        for (int jb = 0; jb < n; jb += 8) {
            float xv[8], vv[8];
            #pragma unroll
            for (int k = 0; k < 8; ++k) {
                int j = jb + k;                    // jb<=56 so j<=63 always
                int   c = __shfl((int)e.x, j);
                vv[k]   = __uint_as_float(__shfl((int)e.y, j));
                xv[k]   = x[((size_t)c << 6) + lane];
            }
            #pragma unroll
            for (int k = 0; k < 8; ++k) acc += vv[k] * xv[k];
        }
    }
    out[((size_t)r << 6) + lane] = acc;
}

// ---------------- fallback: round-1 atomic scatter ----------------
__global__ void spmm_scatter_kernel(const int* __restrict__ rows, const int* __restrict__ cols,
                                    const float* __restrict__ vals,
                                    const float* __restrict__ s_emb, const float* __restrict__ p_emb,
                                    float* __restrict__ out_s, float* __restrict__ out_p, int nnz) {
    long long t = (long long)blockIdx.x * blockDim.x + threadIdx.x;
    int e = (int)(t >> 6);
    int d = (int)(t & 63);
    if (e >= nnz) return;
    int r = rows[e];
    int c = cols[e];
    float v = vals[e];
    atomicAdd(&out_s[(size_t)r * 64 + d], v * p_emb[(size_t)c * 64 + d]);
    atomicAdd(&out_p[(size_t)c * 64 + d], v * s_emb[(size_t)r * 64 + d]);
}

// ---------------- host ----------------
static void run_dir(const int* key, const int* other, const float* vals,
                    const float* x, float* out, int nrows, int nnz, int rsh,
                    uint2* edges1, uint2* edges2, int* gcnt, int* boffs,
                    int* bcursor, int* offs, hipStream_t stream) {
    int nb = (nrows + (1 << rsh) - 1) >> rsh;
    hipMemsetAsync(gcnt, 0, NBMAX * sizeof(int), stream);
    bucket_hist<<<512, NBMAX, 0, stream>>>(key, gcnt, nnz, rsh);
    scan_offs<<<1, NBMAX, 0, stream>>>(gcnt, boffs, bcursor, nb, nnz);
    int ntiles = (nnz + TILE - 1) / TILE;
    staged_scatter<<<ntiles, 256, 0, stream>>>(key, other, vals, bcursor, edges1, nnz, rsh);
    row_scatter<<<nb, 1024, 0, stream>>>(edges1, boffs, edges2, offs, nrows, rsh, nb);
    row_gather<<<(nrows + 3) / 4, 256, 0, stream>>>(offs, edges2, x, out, nrows);
}

extern "C" void kernel_launch(void* const* d_in, const int* in_sizes, int n_in,
                              void* d_out, int out_size, void* d_ws, size_t ws_size,
                              hipStream_t stream) {
    const float* s_emb   = (const float*)d_in[0];
    const float* p_emb   = (const float*)d_in[1];
    const int*   a_rows  = (const int*)d_in[2];
    const int*   a_cols  = (const int*)d_in[3];
    const float* a_vals  = (const float*)d_in[4];
    const int*   ia_rows = (const int*)d_in[5];
    const int*   ia_cols = (const int*)d_in[6];
    const float* ia_vals = (const float*)d_in[7];

    const int NS  = in_sizes[0] / 64;
    const int NP  = in_sizes[1] / 64;
    const int nnz = in_sizes[2];

    float* out = (float*)d_out;
    float* out_sc  = out;
    float* out_sic = out_sc  + (size_t)NS * 64;
    float* out_pc  = out_sic + (size_t)NS * 64;
    float* out_pic = out_pc  + (size_t)NP * 64;

    // choose smallest bucket shift with nb <= NBMAX (lrow must fit 8 bits)
    int rsh_s = 0; while ((((long long)NS + (1LL << rsh_s) - 1) >> rsh_s) > NBMAX) rsh_s++;
    int rsh_p = 0; while ((((long long)NP + (1LL << rsh_p) - 1) >> rsh_p) > NBMAX) rsh_p++;

    const int Nmax = (NS > NP) ? NS : NP;
    const size_t need = 2 * (size_t)nnz * sizeof(uint2)
                      + (size_t)(Nmax + 1) * sizeof(int)
                      + (3 * NBMAX + 2) * sizeof(int) + 256;
    const bool packable = (rsh_s <= 8) && (rsh_p <= 8) && (NS <= 0xFFFF) && (NP <= 0xFFFF);

    if (ws_size < need || !packable) {
        hipMemsetAsync(d_out, 0, (size_t)out_size * sizeof(float), stream);
        const long long total = (long long)nnz * 64;
        const int grid = (int)((total + 255) / 256);
        spmm_scatter_kernel<<<grid, 256, 0, stream>>>(a_rows, a_cols, a_vals, s_emb, p_emb,
                                                      out_sc, out_pc, nnz);
        spmm_scatter_kernel<<<grid, 256, 0, stream>>>(ia_rows, ia_cols, ia_vals, s_emb, p_emb,
                                                      out_sic, out_pic, nnz);
        return;
    }

    char* w = (char*)d_ws;
    uint2* edges1 = (uint2*)w;  w += (size_t)nnz * sizeof(uint2);
    uint2* edges2 = (uint2*)w;  w += (size_t)nnz * sizeof(uint2);
    int*   offs   = (int*)w;    w += (size_t)(Nmax + 1) * sizeof(int);
    int*   gcnt   = (int*)w;    w += NBMAX * sizeof(int);
    int*   boffs  = (int*)w;    w += (NBMAX + 1) * sizeof(int);
    int*   bcursor= (int*)w;

    // outputs: (student_c, student_ic, problem_c, problem_ic)
    run_dir(a_rows,  a_cols,  a_vals,  p_emb, out_sc,  NS, nnz, rsh_s,
            edges1, edges2, gcnt, boffs, bcursor, offs, stream);
    run_dir(a_cols,  a_rows,  a_vals,  s_emb, out_pc,  NP, nnz, rsh_p,
            edges1, edges2, gcnt, boffs, bcursor, offs, stream);
    run_dir(ia_rows, ia_cols, ia_vals, p_emb, out_sic, NS, nnz, rsh_s,
            edges1, edges2, gcnt, boffs, bcursor, offs, stream);
    run_dir(ia_cols, ia_rows, ia_vals, s_emb, out_pic, NP, nnz, rsh_p,
            edges1, edges2, gcnt, boffs, bcursor, offs, stream);
}

// Round 5
// 751.291 us; speedup vs baseline: 8.1042x; 1.1466x over previous
//
#include <hip/hip_runtime.h>
#include <hip/hip_bf16.h>

#define NBMAX 256   // coarse buckets per direction
#define BINS2 512   // max (rows-per-bucket x segments) bins in row_scatter
#define TILE  4096  // edges per staged-scatter tile
#define KPT   16    // TILE / 256

// ---------------- phase A1: all-4-direction coarse histogram ----------------
__global__ __launch_bounds__(256) void hist_all(
        const int* __restrict__ k0, const int* __restrict__ k1,
        const int* __restrict__ k2, const int* __restrict__ k3,
        int* __restrict__ gcnt4, int nnz, int rsh_s, int rsh_p) {
    __shared__ int h[NBMAX];
    int dir = blockIdx.x & 3;
    const int* key = (dir == 0) ? k0 : (dir == 1) ? k1 : (dir == 2) ? k2 : k3;
    int rsh = (dir & 1) ? rsh_p : rsh_s;
    h[threadIdx.x] = 0;
    __syncthreads();
    int ch = blockIdx.x >> 2, nch = gridDim.x >> 2;
    for (int i = ch * 256 + threadIdx.x; i < nnz; i += nch * 256)
        atomicAdd(&h[key[i] >> rsh], 1);
    __syncthreads();
    int v = h[threadIdx.x];
    if (v) atomicAdd(&gcnt4[dir * NBMAX + threadIdx.x], v);
}

// ---------------- phase A2: bucket offsets for all 4 dirs (4 blocks) --------
__global__ __launch_bounds__(256) void scan_all(
        const int* __restrict__ gcnt4, int* __restrict__ boffs4,
        int* __restrict__ bcur4, int nb_s, int nb_p, int nnz) {
    __shared__ int tmp[NBMAX];
    int dir = blockIdx.x, tid = threadIdx.x;
    int nb = (dir & 1) ? nb_p : nb_s;
    int v = (tid < nb) ? gcnt4[dir * NBMAX + tid] : 0;
    tmp[tid] = v;
    __syncthreads();
    for (int off = 1; off < NBMAX; off <<= 1) {
        int t = (tid >= off) ? tmp[tid - off] : 0;
        __syncthreads();
        tmp[tid] += t;
        __syncthreads();
    }
    if (tid < nb) {
        int e = tmp[tid] - v;
        boffs4[dir * (NBMAX + 1) + tid] = e;
        bcur4[dir * NBMAX + tid] = e;
    }
    if (tid == 0) boffs4[dir * (NBMAX + 1) + nb] = nnz;
}

// ---------------- phase A3: staged coalesced bucket scatter (rank-trick) ----
// hist atomicAdd's return value IS the within-(tile,bucket) rank: one LDS
// atomic round instead of two. pack e.x = other | (lrow << 16).
__global__ __launch_bounds__(256) void staged_scatter(
        const int* __restrict__ key, const int* __restrict__ other,
        const float* __restrict__ vals, int* __restrict__ cursor,
        uint2* __restrict__ edges, int nnz, int rsh) {
    __shared__ int lhist[NBMAX], lofs[NBMAX], lbase[NBMAX];
    __shared__ uint2 stage[TILE];
    __shared__ int   sslot[TILE];
    int tid = threadIdx.x;
    int lmask = (1 << rsh) - 1;
    int ntiles = (nnz + TILE - 1) / TILE;
    for (int tile = blockIdx.x; tile < ntiles; tile += gridDim.x) {
        int tbeg = tile * TILE;
        int n = nnz - tbeg; if (n > TILE) n = TILE;
        lhist[tid] = 0;
        __syncthreads();
        int myb[KPT], myr[KPT]; unsigned myo[KPT]; float myv[KPT];
        #pragma unroll
        for (int k = 0; k < KPT; ++k) {
            int s = k * 256 + tid;
            if (s < n) {
                int i = tbeg + s;
                int ky = key[i];
                myb[k] = ky >> rsh;
                myo[k] = (unsigned)other[i] | ((unsigned)(ky & lmask) << 16);
                myv[k] = vals[i];
                myr[k] = atomicAdd(&lhist[myb[k]], 1);   // rank within (tile,bucket)
            } else myb[k] = -1;
        }
        __syncthreads();
        int h = lhist[tid];
        lofs[tid] = h;
        __syncthreads();
        for (int off = 1; off < NBMAX; off <<= 1) {
            int t = (tid >= off) ? lofs[tid - off] : 0;
            __syncthreads();
            lofs[tid] += t;
            __syncthreads();
        }
        lofs[tid] -= h;                                   // exclusive
        if (h > 0) lbase[tid] = atomicAdd(&cursor[tid], h);
        __syncthreads();
        #pragma unroll
        for (int k = 0; k < KPT; ++k) {
            if (myb[k] >= 0) {
                int ls = lofs[myb[k]] + myr[k];
                stage[ls] = make_uint2(myo[k], __float_as_uint(myv[k]));
                sslot[ls] = lbase[myb[k]] + myr[k];
            }
        }
        __syncthreads();
        #pragma unroll
        for (int k = 0; k < KPT; ++k) {
            int s = k * 256 + tid;
            if (s < n) edges[sslot[s]] = stage[s];        // coalesced bucket runs
        }
        __syncthreads();
    }
}

// ---------------- phase B: within-bucket sort by (row, src-segment) ---------
// bin = lrow * S + (other >> sshift). Segment-ordering within each row makes
// co-resident gather waves sweep x in near-lockstep -> L2-resident working
// set. Gather interface (per-row offs) unchanged: seg order is internal.
__global__ __launch_bounds__(1024) void row_scatter(
        const uint2* __restrict__ e1, const int* __restrict__ boffs,
        uint2* __restrict__ e2, int* __restrict__ offs,
        int nrows, int rsh, int nb, int S, int sshift) {
    __shared__ int lh[BINS2], lcur[BINS2], tmp[BINS2];
    int tid = threadIdx.x, b = blockIdx.x;
    int rpb = 1 << rsh;
    int bins = rpb * S;
    int beg = boffs[b], end = boffs[b + 1];
    for (int i = tid; i < bins; i += 1024) lh[i] = 0;
    __syncthreads();
    for (int i = beg + tid; i < end; i += 1024) {
        uint2 e = e1[i];
        int bin = (int)(e.x >> 16) * S + (int)((e.x & 0xFFFFu) >> sshift);
        atomicAdd(&lh[bin], 1);
    }
    __syncthreads();
    for (int i = tid; i < bins; i += 1024) tmp[i] = lh[i];
    __syncthreads();
    for (int off = 1; off < bins; off <<= 1) {            // bins <= 512 <= 1024
        int t = (tid < bins && tid >= off) ? tmp[tid - off] : 0;
        __syncthreads();
        if (tid < bins) tmp[tid] += t;
        __syncthreads();
    }
    if (tid < bins) lcur[tid] = beg + tmp[tid] - lh[tid]; // exclusive base
    __syncthreads();
    if (tid < rpb) {
        int row = (b << rsh) + tid;
        if (row < nrows) offs[row] = lcur[tid * S];
    }
    if (b == 0 && tid == 0) offs[nrows] = boffs[nb];
    __syncthreads();
    for (int i = beg + tid; i < end; i += 1024) {
        uint2 e = e1[i];
        int bin = (int)(e.x >> 16) * S + (int)((e.x & 0xFFFFu) >> sshift);
        int slot = atomicAdd(&lcur[bin], 1);
        e2[slot] = make_uint2(e.x & 0xFFFFu, e.y);        // stores land in L2-resident span
    }
}

// ---------------- phase C: per-row wave gather, 8-deep pipelined ------------
__global__ __launch_bounds__(256) void row_gather(
        const int* __restrict__ offs, const uint2* __restrict__ edges,
        const float* __restrict__ x, float* __restrict__ out, int nrows) {
    int r = blockIdx.x * 4 + (threadIdx.x >> 6);
    int lane = threadIdx.x & 63;
    if (r >= nrows) return;
    int beg = offs[r], end = offs[r + 1];
    float acc = 0.f;
    for (int base = beg; base < end; base += 64) {
        int n = end - base; if (n > 64) n = 64;
        uint2 e = make_uint2(0u, 0u);
        if (lane < n) e = edges[base + lane];
        for (int jb = 0; jb < n; jb += 8) {
            float xv[8], vv[8];
            #pragma unroll
            for (int k = 0; k < 8; ++k) {
                int j = jb + k;
                int   c = __shfl((int)e.x, j);
                vv[k]   = __uint_as_float(__shfl((int)e.y, j));
                xv[k]   = x[((size_t)c << 6) + lane];
            }
            #pragma unroll
            for (int k = 0; k < 8; ++k) acc += vv[k] * xv[k];
        }
    }
    out[((size_t)r << 6) + lane] = acc;
}

// ---------------- fallback: round-1 atomic scatter ----------------
__global__ void spmm_scatter_kernel(const int* __restrict__ rows, const int* __restrict__ cols,
                                    const float* __restrict__ vals,
                                    const float* __restrict__ s_emb, const float* __restrict__ p_emb,
                                    float* __restrict__ out_s, float* __restrict__ out_p, int nnz) {
    long long t = (long long)blockIdx.x * blockDim.x + threadIdx.x;
    int e = (int)(t >> 6);
    int d = (int)(t & 63);
    if (e >= nnz) return;
    int r = rows[e];
    int c = cols[e];
    float v = vals[e];
    atomicAdd(&out_s[(size_t)r * 64 + d], v * p_emb[(size_t)c * 64 + d]);
    atomicAdd(&out_p[(size_t)c * 64 + d], v * s_emb[(size_t)r * 64 + d]);
}

// ---------------- host ----------------
extern "C" void kernel_launch(void* const* d_in, const int* in_sizes, int n_in,
                              void* d_out, int out_size, void* d_ws, size_t ws_size,
                              hipStream_t stream) {
    const float* s_emb   = (const float*)d_in[0];
    const float* p_emb   = (const float*)d_in[1];
    const int*   a_rows  = (const int*)d_in[2];
    const int*   a_cols  = (const int*)d_in[3];
    const float* a_vals  = (const float*)d_in[4];
    const int*   ia_rows = (const int*)d_in[5];
    const int*   ia_cols = (const int*)d_in[6];
    const float* ia_vals = (const float*)d_in[7];

    const int NS  = in_sizes[0] / 64;
    const int NP  = in_sizes[1] / 64;
    const int nnz = in_sizes[2];

    float* out = (float*)d_out;
    float* out_sc  = out;
    float* out_sic = out_sc  + (size_t)NS * 64;
    float* out_pc  = out_sic + (size_t)NS * 64;
    float* out_pic = out_pc  + (size_t)NP * 64;

    // bucket shifts: smallest with nb <= NBMAX (NS: 8 -> 196 bkts; NP: 6 -> 157)
    int rsh_s = 0; while ((((long long)NS + (1LL << rsh_s) - 1) >> rsh_s) > NBMAX) rsh_s++;
    int rsh_p = 0; while ((((long long)NP + (1LL << rsh_p) - 1) >> rsh_p) > NBMAX) rsh_p++;
    int nb_s = (NS + (1 << rsh_s) - 1) >> rsh_s;
    int nb_p = (NP + (1 << rsh_p) - 1) >> rsh_p;

    // student dirs: no seg ordering (p_emb is L2-resident)
    int sshift_s = 0; while ((NP - 1) >> sshift_s) sshift_s++;       // -> seg == 0
    // problem dirs: segment s_emb into ~2MB slices (8192 rows)
    int sshift_p = 13;
    int S_p = ((NS - 1) >> sshift_p) + 1;
    while ((S_p << rsh_p) > BINS2) { sshift_p++; S_p = ((NS - 1) >> sshift_p) + 1; }

    const int Nmax = (NS > NP) ? NS : NP;
    const size_t need = 2 * (size_t)nnz * sizeof(uint2)
                      + (size_t)(Nmax + 1) * sizeof(int)
                      + (size_t)(4 * NBMAX + 4 * (NBMAX + 1) + 4 * NBMAX) * sizeof(int) + 256;
    const bool packable = (NS <= 0xFFFF) && (NP <= 0xFFFF) &&
                          (rsh_s <= 8) && (rsh_p <= 8) &&
                          ((1 << rsh_s) <= BINS2) && ((S_p << rsh_p) <= BINS2);

    if (ws_size < need || !packable) {
        hipMemsetAsync(d_out, 0, (size_t)out_size * sizeof(float), stream);
        const long long total = (long long)nnz * 64;
        const int grid = (int)((total + 255) / 256);
        spmm_scatter_kernel<<<grid, 256, 0, stream>>>(a_rows, a_cols, a_vals, s_emb, p_emb,
                                                      out_sc, out_pc, nnz);
        spmm_scatter_kernel<<<grid, 256, 0, stream>>>(ia_rows, ia_cols, ia_vals, s_emb, p_emb,
                                                      out_sic, out_pic, nnz);
        return;
    }

    char* w = (char*)d_ws;
    uint2* edges1 = (uint2*)w;  w += (size_t)nnz * sizeof(uint2);
    uint2* edges2 = (uint2*)w;  w += (size_t)nnz * sizeof(uint2);
    int*   offs   = (int*)w;    w += (size_t)(Nmax + 1) * sizeof(int);
    int*   gcnt4  = (int*)w;    w += 4 * NBMAX * sizeof(int);
    int*   boffs4 = (int*)w;    w += 4 * (NBMAX + 1) * sizeof(int);
    int*   bcur4  = (int*)w;

    hipMemsetAsync(gcnt4, 0, 4 * NBMAX * sizeof(int), stream);
    // dirs: 0 = a by row, 1 = a by col, 2 = ia by row, 3 = ia by col
    hist_all<<<1024, 256, 0, stream>>>(a_rows, a_cols, ia_rows, ia_cols,
                                       gcnt4, nnz, rsh_s, rsh_p);
    scan_all<<<4, 256, 0, stream>>>(gcnt4, boffs4, bcur4, nb_s, nb_p, nnz);

    const int ntiles = (nnz + TILE - 1) / TILE;
    struct Dir { const int* key; const int* other; const float* vals;
                 const float* x; float* out; int nrows, rsh, nb, S, sshift; };
    // output order: (student_c, student_ic, problem_c, problem_ic)
    Dir dirs[4] = {
        { a_rows,  a_cols,  a_vals,  p_emb, out_sc,  NS, rsh_s, nb_s, 1,   sshift_s },
        { a_cols,  a_rows,  a_vals,  s_emb, out_pc,  NP, rsh_p, nb_p, S_p, sshift_p },
        { ia_rows, ia_cols, ia_vals, p_emb, out_sic, NS, rsh_s, nb_s, 1,   sshift_s },
        { ia_cols, ia_rows, ia_vals, s_emb, out_pic, NP, rsh_p, nb_p, S_p, sshift_p },
    };
    // dispatch index within boffs4/bcur4 blocks (hist dirs: 0=a_row,1=a_col,2=ia_row,3=ia_col)
    int hd[4] = { 0, 1, 2, 3 };
    for (int t = 0; t < 4; ++t) {
        const Dir& D = dirs[t];
        int d = hd[t];
        staged_scatter<<<ntiles, 256, 0, stream>>>(D.key, D.other, D.vals,
                                                   bcur4 + d * NBMAX, edges1, nnz, D.rsh);
        row_scatter<<<D.nb, 1024, 0, stream>>>(edges1, boffs4 + d * (NBMAX + 1),
                                               edges2, offs, D.nrows, D.rsh, D.nb,
                                               D.S, D.sshift);
        row_gather<<<(D.nrows + 3) / 4, 256, 0, stream>>>(offs, edges2, D.x, D.out, D.nrows);
    }
}